// Round 4
// baseline (827.996 us; speedup 1.0000x reference)
//
#include <hip/hip_runtime.h>
#include <hip/hip_bf16.h>
#include <stdint.h>

typedef unsigned int u32;
typedef unsigned short u16;
typedef short short8 __attribute__((ext_vector_type(8)));
typedef float f32x4 __attribute__((ext_vector_type(4)));

#define NN 50000
#define NE 200000
#define WCT 576     // 256 fsrc | 256 res | 8 e_src | 8 e_dst | 48 pad (cols of C)

__device__ __forceinline__ float leaky(float x){ return x >= 0.f ? x : 0.2f*x; }
__device__ __forceinline__ float bf2f(u16 u){ return __uint_as_float(((u32)u)<<16); }
__device__ __forceinline__ u16 f2bf(float f){            // RNE
    u32 u = __float_as_uint(f);
    u32 r = (u + 0x7fffu + ((u>>16)&1u)) >> 16;
    return (u16)r;
}
// pack 2 floats -> 2 bf16 (truncation) in ONE v_perm_b32
__device__ __forceinline__ u32 pack_bf2(float a, float b){
    return __builtin_amdgcn_perm(__float_as_uint(b), __float_as_uint(a), 0x07060302u);
}
__device__ __forceinline__ int nt_src(int r){ return (r==0)?0:((r==3)?2:1); }
__device__ __forceinline__ int nt_dst(int r){ return (r==1)?0:((r==2)?2:1); }

// ra[r][512] = rel_emb[r] @ rel_W[r]
__global__ void k_ra(const float* __restrict__ rel_emb, const float* __restrict__ rel_W,
                     float* __restrict__ ra){
    int r = blockIdx.x;
    for (int j = threadIdx.x; j < 512; j += blockDim.x){
        float acc = 0.f;
        for (int i = 0; i < 64; i++) acc += rel_emb[r*64+i] * rel_W[(r*64+i)*512 + j];
        ra[r*512 + j] = acc;
    }
}

// Assemble WcatT[r] (576 x 256, bf16, transposed so B-frag reads are K-contiguous):
// rows: [node_W[s] | res_W[d] | w_src_eff(8) | w_dst_eff(8) | 0-pad]
__global__ void k_wcat(const float* __restrict__ node_W, const float* __restrict__ res_W,
                       const float* __restrict__ ra, u16* __restrict__ WcatT){
    int g = blockIdx.x*blockDim.x + threadIdx.x;
    if (g >= 4*WCT*256) return;
    int r = g/(WCT*256); int rem = g%(WCT*256); int n = rem/256; int k = rem%256;
    int s = nt_src(r), d = nt_dst(r);
    float v;
    if (n < 256) v = node_W[(s*256+k)*256 + n];
    else if (n < 512) v = res_W[(d*256+k)*256 + (n-256)];
    else if (n < 520){ // e_src weights: node_W[s]·ra[h, D:]
        int h = n-512; float a = 0.f;
        for (int dd = 0; dd < 32; dd++) a += node_W[(s*256+k)*256 + h*32+dd] * ra[r*512 + h*64+32+dd];
        v = a;
    } else if (n < 528){ // e_dst weights: node_W[d]·ra[h, :D]
        int h = n-520; float a = 0.f;
        for (int dd = 0; dd < 32; dd++) a += node_W[(d*256+k)*256 + h*32+dd] * ra[r*512 + h*64+dd];
        v = a;
    } else v = 0.f;
    WcatT[(size_t)(r*WCT+n)*256 + k] = f2bf(v);
}

// MFMA GEMM, A-resident: one block owns 64 rows; A(64x256 bf16) stays in LDS
// across all 9 n-tiles; B(64x256 bf16) restaged per tile (L2-resident).
// 4 waves 2x2 over the 64x64 tile. XOR-swizzled LDS (16B chunk ^ (row&7)).
__launch_bounds__(256)
__global__ void k_gemm(const float* __restrict__ feat, const u16* __restrict__ WcatT,
                       const float* __restrict__ res_b,
                       u16* __restrict__ fsrc, u16* __restrict__ resb,
                       float* __restrict__ e_src, float* __restrict__ e_dst){
    __shared__ uint4 lsA[2048];   // 64 rows x 32 chunks(16B) = 32KB
    __shared__ uint4 lsB[2048];   // 64 n-rows x 32 chunks     = 32KB
    const short8* lsA8 = (const short8*)lsA;
    const short8* lsB8 = (const short8*)lsB;

    int r = blockIdx.y;
    int row0 = blockIdx.x*64;
    const float* A = feat + (size_t)r*NN*256;
    const u16*   W = WcatT + (size_t)r*WCT*256;

    int t = threadIdx.x;
    int w = t>>6, l = t&63;
    int wm = (w>>1)*32, wn = (w&1)*32;
    int li = l & 15, lg = l >> 4;

    // ---- stage A once: thread t -> row t>>2, 64-float k-segment (t&3)*64
    int arow = t>>2;
    int ks   = (t&3)*64;
    int ag = row0 + arow; if (ag > NN-1) ag = NN-1;
    const float* asrc = A + (size_t)ag*256 + ks;
    #pragma unroll
    for (int h = 0; h < 2; h++){
        float4 av[8];
        #pragma unroll
        for (int i = 0; i < 8; i++) av[i] = *(const float4*)(asrc + h*32 + i*4);
        #pragma unroll
        for (int i = 0; i < 4; i++){
            uint4 pk;
            pk.x = pack_bf2(av[2*i].x,   av[2*i].y);
            pk.y = pack_bf2(av[2*i].z,   av[2*i].w);
            pk.z = pack_bf2(av[2*i+1].x, av[2*i+1].y);
            pk.w = pack_bf2(av[2*i+1].z, av[2*i+1].w);
            int c = (t&3)*8 + h*4 + i;
            lsA[arow*32 + (c ^ (arow&7))] = pk;
        }
    }

    int d = nt_dst(r);
    int brow = t>>2;
    // ---- loop over the 9 n-tiles, A stays resident
    for (int nt9 = 0; nt9 < 9; nt9++){
        int n0 = nt9*64;
        // load B tile to regs (from L2): thread t -> n-row t>>2, 128B seg (t&3)*64 u16
        const uint4* bsrc = (const uint4*)(W + (size_t)(n0+brow)*256 + (t&3)*64);
        uint4 bv[8];
        #pragma unroll
        for (int i = 0; i < 8; i++) bv[i] = bsrc[i];
        __syncthreads();   // prev compute done reading lsB (iter0: lsA writes visible too)
        #pragma unroll
        for (int i = 0; i < 8; i++){
            int c = (t&3)*8 + i;
            lsB[brow*32 + (c ^ (brow&7))] = bv[i];
        }
        __syncthreads();

        f32x4 acc[2][2] = {};
        #pragma unroll
        for (int kk = 0; kk < 8; kk++){
            int kc = kk*4 + lg;
            short8 bfr[2], afr[2];
            #pragma unroll
            for (int nt = 0; nt < 2; nt++){
                int nrow = wn + nt*16 + li;
                bfr[nt] = lsB8[nrow*32 + (kc ^ (nrow&7))];
            }
            #pragma unroll
            for (int mt = 0; mt < 2; mt++){
                int mrow = wm + mt*16 + li;
                afr[mt] = lsA8[mrow*32 + (kc ^ (mrow&7))];
            }
            #pragma unroll
            for (int mt = 0; mt < 2; mt++)
                #pragma unroll
                for (int nt = 0; nt < 2; nt++)
                    acc[mt][nt] = __builtin_amdgcn_mfma_f32_16x16x32_bf16(afr[mt], bfr[nt], acc[mt][nt], 0,0,0);
        }

        // epilogue for this n-tile
        #pragma unroll
        for (int mt = 0; mt < 2; mt++){
            #pragma unroll
            for (int nt = 0; nt < 2; nt++){
                #pragma unroll
                for (int q = 0; q < 4; q++){
                    int row = row0 + wm + mt*16 + lg*4 + q;
                    if (row >= NN) continue;
                    int col = n0 + wn + nt*16 + li;
                    float v = acc[mt][nt][q];
                    size_t nidx = (size_t)r*NN + row;
                    if (col < 256)      fsrc[nidx*256 + col] = f2bf(v);
                    else if (col < 512) resb[nidx*256 + (col-256)] = f2bf(v + res_b[d*256 + (col-256)]);
                    else if (col < 520) e_src[nidx*8 + (col-512)] = v;
                    else if (col < 528) e_dst[nidx*8 + (col-520)] = v;
                }
            }
        }
    }
}

// ---- CSR build: count -> hierarchical scan -> scatter ----

__global__ void k_count(const int* __restrict__ dst_idx, u32* __restrict__ cnt){
    int r = blockIdx.y; int e = blockIdx.x*256 + threadIdx.x;
    if (e >= NE) return;
    atomicAdd(&cnt[r*NN + dst_idx[r*NE+e]], 1u);
}

__global__ void k_scan1(const u32* __restrict__ cnt, u32* __restrict__ bsum){
    int r = blockIdx.y, b = blockIdx.x;
    int i = b*256 + threadIdx.x;
    u32 v = (i < NN) ? cnt[r*NN+i] : 0u;
    #pragma unroll
    for (int off = 1; off < 64; off <<= 1) v += __shfl_xor(v, off, 64);
    __shared__ u32 wsum[4];
    int lane = threadIdx.x & 63, w = threadIdx.x >> 6;
    if (lane == 0) wsum[w] = v;
    __syncthreads();
    if (threadIdx.x == 0) bsum[r*256 + b] = wsum[0]+wsum[1]+wsum[2]+wsum[3];
}

__device__ __forceinline__ u32 block_scan_incl(u32 v){
    __shared__ u32 wsum[4];
    int lane = threadIdx.x & 63, w = threadIdx.x >> 6;
    #pragma unroll
    for (int off = 1; off < 64; off <<= 1){
        u32 t = __shfl_up(v, off, 64);
        if (lane >= off) v += t;
    }
    if (lane == 63) wsum[w] = v;
    __syncthreads();
    u32 add = 0;
    #pragma unroll
    for (int k = 0; k < 4; k++) if (k < w) add += wsum[k];
    return v + add;
}

__global__ void k_scan2(u32* __restrict__ bsum){
    int r = blockIdx.x;
    u32 v = bsum[r*256 + threadIdx.x];
    u32 incl = block_scan_incl(v);
    bsum[r*256 + threadIdx.x] = incl - v;
}

__global__ void k_scan3(const u32* __restrict__ cnt, const u32* __restrict__ bsum,
                        u32* __restrict__ row_ptr){
    int r = blockIdx.y, b = blockIdx.x;
    int i = b*256 + threadIdx.x;
    u32 v = (i < NN) ? cnt[r*NN+i] : 0u;
    u32 incl = block_scan_incl(v);
    if (i < NN) row_ptr[r*(NN+1) + i + 1] = bsum[r*256 + b] + incl;
    if (b == 0 && threadIdx.x == 0) row_ptr[r*(NN+1)] = 0u;
}

__global__ void k_scatter(const int* __restrict__ src_idx, const int* __restrict__ dst_idx,
                          const float* __restrict__ e_src, const float* __restrict__ e_dst,
                          const u32* __restrict__ row_ptr, u32* __restrict__ cnt2,
                          u32* __restrict__ src_pack, float* __restrict__ e_pack){
    int r = blockIdx.y; int e = blockIdx.x*256 + threadIdx.x;
    if (e >= NE) return;
    int s = src_idx[r*NE+e], d = dst_idx[r*NE+e];
    u32 pos = row_ptr[r*(NN+1)+d] + atomicAdd(&cnt2[r*NN+d], 1u);
    src_pack[r*NE + pos] = (u32)s;
    const float* es = e_src + ((size_t)r*NN+s)*8;
    const float* ed = e_dst + ((size_t)r*NN+d)*8;
    float* ep = e_pack + ((size_t)(r*NE)+pos)*8;
    #pragma unroll
    for (int h = 0; h < 8; h++) ep[h] = leaky(es[h] + ed[h]);
}

// one wave per (node, rel): inline segment softmax + aggregation + relu + residual gate.
__launch_bounds__(256)
__global__ void k_agg(const u32* __restrict__ row_ptr, const u32* __restrict__ src_pack,
                      const float* __restrict__ e_pack, const u16* __restrict__ fsrc,
                      const u16* __restrict__ resb, const float* __restrict__ res_alpha,
                      float* __restrict__ out){
    int r = blockIdx.y;
    int wid = threadIdx.x >> 6;
    int n = blockIdx.x*4 + wid;
    if (n >= NN) return;
    int l = threadIdx.x & 63;
    u32 p0 = row_ptr[r*(NN+1)+n];
    u32 p1 = row_ptr[r*(NN+1)+n+1];
    int deg = (int)(p1 - p0);

    float m = -1e30f, s = 0.f;
    for (int i = (l>>3); i < deg; i += 8){
        float e = e_pack[((size_t)(r*NE) + p0 + i)*8 + (l&7)];
        float mn = fmaxf(m, e);
        s = s*__expf(m - mn) + __expf(e - mn);
        m = mn;
    }
    #pragma unroll
    for (int msk = 8; msk < 64; msk <<= 1){
        float m2 = __shfl_xor(m, msk, 64);
        float s2 = __shfl_xor(s, msk, 64);
        float mn = fmaxf(m, m2);
        s = s*__expf(m - mn) + s2*__expf(m2 - mn);
        m = mn;
    }
    int h = l >> 3;
    float mh = __shfl(m, h, 64);
    float sh = __shfl(s, h, 64);

    float a0=0.f, a1=0.f, a2=0.f, a3=0.f;
    for (int i = 0; i < deg; i++){
        size_t ep = (size_t)(r*NE) + p0 + i;
        float a = __expf(e_pack[ep*8 + h] - mh) / sh;
        u32 src = src_pack[ep];
        ushort4 f = *(const ushort4*)(fsrc + ((size_t)r*NN+src)*256 + l*4);
        a0 += bf2f(f.x)*a; a1 += bf2f(f.y)*a; a2 += bf2f(f.z)*a; a3 += bf2f(f.w)*a;
    }
    int d = nt_dst(r);
    float alpha = 1.f/(1.f + __expf(-res_alpha[d]));
    float beta = 1.f - alpha;
    ushort4 rv = *(const ushort4*)(resb + ((size_t)r*NN+n)*256 + l*4);
    float4 o;
    o.x = fmaxf(a0,0.f)*alpha + bf2f(rv.x)*beta;
    o.y = fmaxf(a1,0.f)*alpha + bf2f(rv.y)*beta;
    o.z = fmaxf(a2,0.f)*alpha + bf2f(rv.z)*beta;
    o.w = fmaxf(a3,0.f)*alpha + bf2f(rv.w)*beta;
    *(float4*)(out + ((size_t)r*NN+n)*256 + l*4) = o;
}

__global__ void k_cross(float* __restrict__ out, const float* __restrict__ cross_attn){
    int n = blockIdx.x; int t = threadIdx.x;   // t = h*32 + d
    size_t i0 = (size_t)n*256 + t;
    size_t i3 = (size_t)3*NN*256 + (size_t)n*256 + t;
    float v0 = out[i0], v3 = out[i3];
    float ca0 = cross_attn[t];
    float ca3 = cross_attn[3*256 + t];
    float p00 = v0*ca0, p30 = v3*ca0, p03 = v0*ca3, p33 = v3*ca3;
    #pragma unroll
    for (int m = 16; m >= 1; m >>= 1){
        p00 += __shfl_xor(p00, m, 64);
        p30 += __shfl_xor(p30, m, 64);
        p03 += __shfl_xor(p03, m, 64);
        p33 += __shfl_xor(p33, m, 64);
    }
    float l0 = leaky(p00), l3 = leaky(p30);
    float mm = fmaxf(l0, l3);
    float w0 = __expf(l0-mm), w3 = __expf(l3-mm);
    float o0 = (w0*v0 + w3*v3) / (w0+w3);
    float q0 = leaky(p03), q3 = leaky(p33);
    float mq = fmaxf(q0, q3);
    float u0 = __expf(q0-mq), u3 = __expf(q3-mq);
    float o3 = (u0*v0 + u3*v3) / (u0+u3);
    out[i0] = o0; out[i3] = o3;
}

__global__ void k_relout(const float* __restrict__ rel_emb, const float* __restrict__ prop_W,
                         const float* __restrict__ prop_b, float* __restrict__ out){
    int r = blockIdx.x; int o = threadIdx.x;
    float acc = prop_b[r*256 + o];
    for (int i = 0; i < 64; i++) acc += rel_emb[r*64+i] * prop_W[(r*64+i)*256 + o];
    out[(size_t)4*NN*256 + r*256 + o] = acc;
}

extern "C" void kernel_launch(void* const* d_in, const int* in_sizes, int n_in,
                              void* d_out, int out_size, void* d_ws, size_t ws_size,
                              hipStream_t stream){
    const float* feat      = (const float*)d_in[0];
    const float* rel_emb   = (const float*)d_in[1];
    const float* node_W    = (const float*)d_in[2];
    const float* rel_W     = (const float*)d_in[3];
    const float* res_W     = (const float*)d_in[4];
    const float* res_b     = (const float*)d_in[5];
    const float* res_alpha = (const float*)d_in[6];
    const float* cross_attn= (const float*)d_in[7];
    const float* prop_W    = (const float*)d_in[8];
    const float* prop_b    = (const float*)d_in[9];
    const int* src_idx     = (const int*)d_in[10];
    const int* dst_idx     = (const int*)d_in[11];
    float* out = (float*)d_out;

    char* ws = (char*)d_ws;
    u32*   cnt     = (u32*)  (ws);                 //    800,000 B (4,NN)
    u32*   cnt2    = (u32*)  (ws + 800000);        //    800,000 B (4,NN)
    u32*   bsum    = (u32*)  (ws + 1600000);       //      4,096 B (4,256)
    u32*   row_ptr = (u32*)  (ws + 1604096);       //    800,016 B (4,NN+1)
    float* ra      = (float*)(ws + 2404112);       //      8,192 B (4,512)
    u16*   WcatT   = (u16*)  (ws + 2412304);       //  1,179,648 B (4,576,256) bf16
    float* e_src   = (float*)(ws + 4771600);       //  6,400,000 B (4,NN,8)
    float* e_dst   = (float*)(ws + 11171600);      //  6,400,000 B (4,NN,8)
    u32*   src_pack= (u32*)  (ws + 17571600);      //  3,200,000 B (4,NE)
    float* e_pack  = (float*)(ws + 20771600);      // 25,600,000 B (4,NE,8)
    u16*   fsrc    = (u16*)  (ws + 46371600);      //102,400,000 B (4,NN,256) bf16
    u16*   resb    = (u16*)  (ws + 148771600);     //102,400,000 B (4,NN,256) bf16
    // total: 251,171,600 B

    hipMemsetAsync(cnt, 0, 1604096, stream);  // cnt + cnt2 + bsum

    k_ra<<<4, 256, 0, stream>>>(rel_emb, rel_W, ra);
    k_wcat<<<(4*WCT*256)/256, 256, 0, stream>>>(node_W, res_W, ra, WcatT);
    dim3 gg((NN+63)/64, 4);
    k_gemm<<<gg, 256, 0, stream>>>(feat, WcatT, res_b, fsrc, resb, e_src, e_dst);

    dim3 geg((NE+255)/256, 4);
    k_count<<<geg, 256, 0, stream>>>(dst_idx, cnt);
    dim3 gsc((NN+255)/256, 4);
    k_scan1<<<gsc, 256, 0, stream>>>(cnt, bsum);
    k_scan2<<<4, 256, 0, stream>>>(bsum);
    k_scan3<<<gsc, 256, 0, stream>>>(cnt, bsum, row_ptr);
    k_scatter<<<geg, 256, 0, stream>>>(src_idx, dst_idx, e_src, e_dst, row_ptr, cnt2,
                                       src_pack, e_pack);
    dim3 ga((NN+3)/4, 4);
    k_agg<<<ga, 256, 0, stream>>>(row_ptr, src_pack, e_pack, fsrc, resb, res_alpha, out);

    k_cross<<<NN, 256, 0, stream>>>(out, cross_attn);
    k_relout<<<4, 256, 0, stream>>>(rel_emb, prop_W, prop_b, out);
}

// Round 5
// 674.597 us; speedup vs baseline: 1.2274x; 1.2274x over previous
//
#include <hip/hip_runtime.h>
#include <hip/hip_bf16.h>
#include <stdint.h>

typedef unsigned int u32;
typedef unsigned short u16;
typedef short short8 __attribute__((ext_vector_type(8)));
typedef float f32x4 __attribute__((ext_vector_type(4)));

#define NN 50000
#define NE 200000
#define WCT 576     // 256 fsrc | 256 res | 8 e_src | 8 e_dst | 48 pad (cols of C)
#define NSTRIP 391  // ceil(50000/128)
#define NWG (9*NSTRIP*4)

__device__ __forceinline__ float leaky(float x){ return x >= 0.f ? x : 0.2f*x; }
__device__ __forceinline__ float bf2f(u16 u){ return __uint_as_float(((u32)u)<<16); }
__device__ __forceinline__ u16 f2bf(float f){            // RNE
    u32 u = __float_as_uint(f);
    u32 r = (u + 0x7fffu + ((u>>16)&1u)) >> 16;
    return (u16)r;
}
// pack 2 floats -> 2 bf16 (truncation) in ONE v_perm_b32
__device__ __forceinline__ u32 pack_bf2(float a, float b){
    return __builtin_amdgcn_perm(__float_as_uint(b), __float_as_uint(a), 0x07060302u);
}
__device__ __forceinline__ int nt_src(int r){ return (r==0)?0:((r==3)?2:1); }
__device__ __forceinline__ int nt_dst(int r){ return (r==1)?0:((r==2)?2:1); }

// ra[r][512] = rel_emb[r] @ rel_W[r]
__global__ void k_ra(const float* __restrict__ rel_emb, const float* __restrict__ rel_W,
                     float* __restrict__ ra){
    int r = blockIdx.x;
    for (int j = threadIdx.x; j < 512; j += blockDim.x){
        float acc = 0.f;
        for (int i = 0; i < 64; i++) acc += rel_emb[r*64+i] * rel_W[(r*64+i)*512 + j];
        ra[r*512 + j] = acc;
    }
}

// Assemble WcatT[r] (576 x 256, bf16, transposed so B-frag reads are K-contiguous)
__global__ void k_wcat(const float* __restrict__ node_W, const float* __restrict__ res_W,
                       const float* __restrict__ ra, u16* __restrict__ WcatT){
    int g = blockIdx.x*blockDim.x + threadIdx.x;
    if (g >= 4*WCT*256) return;
    int r = g/(WCT*256); int rem = g%(WCT*256); int n = rem/256; int k = rem%256;
    int s = nt_src(r), d = nt_dst(r);
    float v;
    if (n < 256) v = node_W[(s*256+k)*256 + n];
    else if (n < 512) v = res_W[(d*256+k)*256 + (n-256)];
    else if (n < 520){ // e_src weights: node_W[s]·ra[h, D:]
        int h = n-512; float a = 0.f;
        for (int dd = 0; dd < 32; dd++) a += node_W[(s*256+k)*256 + h*32+dd] * ra[r*512 + h*64+32+dd];
        v = a;
    } else if (n < 528){ // e_dst weights: node_W[d]·ra[h, :D]
        int h = n-520; float a = 0.f;
        for (int dd = 0; dd < 32; dd++) a += node_W[(d*256+k)*256 + h*32+dd] * ra[r*512 + h*64+dd];
        v = a;
    } else v = 0.f;
    WcatT[(size_t)(r*WCT+n)*256 + k] = f2bf(v);
}

// MFMA GEMM: 128x64 tile, 4 waves 2x2, BK=64, prefetched, XCD-chunk swizzled grid.
// Epilogue: C staged in LDS, stored as dwordx4 (line-complete writes).
__launch_bounds__(256)
__global__ void k_gemm(const float* __restrict__ feat, const u16* __restrict__ WcatT,
                       const float* __restrict__ res_b,
                       u16* __restrict__ fsrc, u16* __restrict__ resb,
                       float* __restrict__ e_comb){
    __shared__ uint4 lsmem[1536];           // 24 KB: lsA[0..1023] | lsB[1024..1535]
    uint4* lsA = lsmem;
    uint4* lsB = lsmem + 1024;
    const short8* lsA8 = (const short8*)lsA;
    const short8* lsB8 = (const short8*)lsB;
    u16* cst = (u16*)lsmem;                 // epilogue C-stage, stride 72 u16

    // bijective XCD-chunk swizzle: 9 n-tiles of a strip -> consecutive slots, one XCD
    int orig = blockIdx.x;
    const int q8 = NWG >> 3, r8 = NWG & 7;
    int xcd = orig & 7, slot = orig >> 3;
    int v = (xcd < r8 ? xcd*(q8+1) : r8*(q8+1) + (xcd-r8)*q8) + slot;
    int nt9 = v % 9;
    int vs  = v / 9;
    int strip = vs % NSTRIP;
    int r = vs / NSTRIP;

    int row0 = strip*128;
    int n0 = nt9*64;
    const float* A = feat + (size_t)r*NN*256;
    const u16*   W = WcatT + (size_t)r*WCT*256;

    int t = threadIdx.x;
    int w = t>>6, l = t&63;
    int wm = (w>>1)*64, wn = (w&1)*32;
    int li = l & 15, lg = l >> 4;

    // staging indices
    int arow = t>>1, ahalf = t&1;               // A: row 0..127, 32-float half
    int ag = row0 + arow; if (ag > NN-1) ag = NN-1;
    const float* asrc = A + (size_t)ag*256 + ahalf*32;
    int bn = t>>2, bc = (t&3)*2;                // B: n-row 0..63, chunk pair
    const u16* bsrc = W + (size_t)(n0+bn)*256 + bc*8;

    // prologue prefetch (k-tile 0)
    float4 av[8]; uint4 bv0, bv1;
    #pragma unroll
    for (int i = 0; i < 8; i++) av[i] = *(const float4*)(asrc + i*4);
    bv0 = *(const uint4*)(bsrc);
    bv1 = *(const uint4*)(bsrc + 8);

    f32x4 acc[4][2] = {};
    for (int k0 = 0; k0 < 256; k0 += 64){
        __syncthreads();
        #pragma unroll
        for (int c = 0; c < 4; c++){
            uint4 pk;
            pk.x = pack_bf2(av[2*c].x,   av[2*c].y);
            pk.y = pack_bf2(av[2*c].z,   av[2*c].w);
            pk.z = pack_bf2(av[2*c+1].x, av[2*c+1].y);
            pk.w = pack_bf2(av[2*c+1].z, av[2*c+1].w);
            int kc = ahalf*4 + c;
            lsA[arow*8 + (kc ^ (arow&7))] = pk;
        }
        lsB[bn*8 + ((bc+0) ^ (bn&7))] = bv0;
        lsB[bn*8 + ((bc+1) ^ (bn&7))] = bv1;
        __syncthreads();
        if (k0 < 192){   // prefetch next k-tile while computing this one
            #pragma unroll
            for (int i = 0; i < 8; i++) av[i] = *(const float4*)(asrc + k0+64 + i*4);
            bv0 = *(const uint4*)(bsrc + k0+64);
            bv1 = *(const uint4*)(bsrc + k0+64 + 8);
        }
        #pragma unroll
        for (int kk = 0; kk < 2; kk++){
            int kc = kk*4 + lg;
            short8 bfr[2], afr[4];
            #pragma unroll
            for (int nt = 0; nt < 2; nt++){
                int nrow = wn + nt*16 + li;
                bfr[nt] = lsB8[nrow*8 + (kc ^ (nrow&7))];
            }
            #pragma unroll
            for (int mt = 0; mt < 4; mt++){
                int mrow = wm + mt*16 + li;
                afr[mt] = lsA8[mrow*8 + (kc ^ (mrow&7))];
            }
            #pragma unroll
            for (int mt = 0; mt < 4; mt++)
                #pragma unroll
                for (int nt = 0; nt < 2; nt++)
                    acc[mt][nt] = __builtin_amdgcn_mfma_f32_16x16x32_bf16(afr[mt], bfr[nt], acc[mt][nt], 0,0,0);
        }
    }

    int d = nt_dst(r);
    if (nt9 == 8){
        // e-tile: cols 512..527 live in nt=0 frags of wn==0 waves.
        // e_comb[node][0..7]=e_src, [8..15]=e_dst  (full 64B-line writes)
        if (wn == 0){
            #pragma unroll
            for (int mt = 0; mt < 4; mt++)
                #pragma unroll
                for (int qq = 0; qq < 4; qq++){
                    int row = row0 + wm + mt*16 + lg*4 + qq;
                    if (row < NN)
                        e_comb[((size_t)r*NN + row)*16 + li] = acc[mt][0][qq];
                }
        }
        return;  // uniform per block: no barriers skipped non-uniformly
    }
    float bias[2] = {0.f, 0.f};
    if (nt9 >= 4){
        bias[0] = res_b[d*256 + (n0-256) + wn + li];
        bias[1] = res_b[d*256 + (n0-256) + wn + 16 + li];
    }
    __syncthreads();   // all MFMA LDS reads done before overwrite
    #pragma unroll
    for (int mt = 0; mt < 4; mt++)
        #pragma unroll
        for (int nt = 0; nt < 2; nt++)
            #pragma unroll
            for (int qq = 0; qq < 4; qq++){
                int lrow = wm + mt*16 + lg*4 + qq;
                cst[lrow*72 + wn + nt*16 + li] = f2bf(acc[mt][nt][qq] + bias[nt]);
            }
    __syncthreads();
    // coalesced store: thread -> (row t>>1, 32-col half t&1), 4x dwordx4
    int orow = t>>1, half = t&1;
    int grow = row0 + orow;
    if (grow < NN){
        size_t nidx = (size_t)r*NN + grow;
        u16* dst = (nt9 < 4) ? (fsrc + nidx*256 + n0) : (resb + nidx*256 + (n0-256));
        const uint4* src = (const uint4*)(cst + orow*72 + half*32);
        uint4* dq = (uint4*)(dst + half*32);
        #pragma unroll
        for (int i = 0; i < 4; i++) dq[i] = src[i];
    }
}

// ---- CSR build: count -> hierarchical scan -> scatter ----

__global__ void k_count(const int* __restrict__ dst_idx, u32* __restrict__ cnt){
    int r = blockIdx.y; int e = blockIdx.x*256 + threadIdx.x;
    if (e >= NE) return;
    atomicAdd(&cnt[r*NN + dst_idx[r*NE+e]], 1u);
}

__global__ void k_scan1(const u32* __restrict__ cnt, u32* __restrict__ bsum){
    int r = blockIdx.y, b = blockIdx.x;
    int i = b*256 + threadIdx.x;
    u32 v = (i < NN) ? cnt[r*NN+i] : 0u;
    #pragma unroll
    for (int off = 1; off < 64; off <<= 1) v += __shfl_xor(v, off, 64);
    __shared__ u32 wsum[4];
    int lane = threadIdx.x & 63, w = threadIdx.x >> 6;
    if (lane == 0) wsum[w] = v;
    __syncthreads();
    if (threadIdx.x == 0) bsum[r*256 + b] = wsum[0]+wsum[1]+wsum[2]+wsum[3];
}

__device__ __forceinline__ u32 block_scan_incl(u32 v){
    __shared__ u32 wsum[4];
    int lane = threadIdx.x & 63, w = threadIdx.x >> 6;
    #pragma unroll
    for (int off = 1; off < 64; off <<= 1){
        u32 t = __shfl_up(v, off, 64);
        if (lane >= off) v += t;
    }
    if (lane == 63) wsum[w] = v;
    __syncthreads();
    u32 add = 0;
    #pragma unroll
    for (int k = 0; k < 4; k++) if (k < w) add += wsum[k];
    return v + add;
}

__global__ void k_scan2(u32* __restrict__ bsum){
    int r = blockIdx.x;
    u32 v = bsum[r*256 + threadIdx.x];
    u32 incl = block_scan_incl(v);
    bsum[r*256 + threadIdx.x] = incl - v;
}

__global__ void k_scan3(const u32* __restrict__ cnt, const u32* __restrict__ bsum,
                        u32* __restrict__ row_ptr){
    int r = blockIdx.y, b = blockIdx.x;
    int i = b*256 + threadIdx.x;
    u32 v = (i < NN) ? cnt[r*NN+i] : 0u;
    u32 incl = block_scan_incl(v);
    if (i < NN) row_ptr[r*(NN+1) + i + 1] = bsum[r*256 + b] + incl;
    if (b == 0 && threadIdx.x == 0) row_ptr[r*(NN+1)] = 0u;
}

__global__ void k_scatter(const int* __restrict__ src_idx, const int* __restrict__ dst_idx,
                          const float* __restrict__ e_comb,
                          const u32* __restrict__ row_ptr, u32* __restrict__ cnt2,
                          u32* __restrict__ src_pack, float* __restrict__ e_pack){
    int r = blockIdx.y; int e = blockIdx.x*256 + threadIdx.x;
    if (e >= NE) return;
    int s = src_idx[r*NE+e], d = dst_idx[r*NE+e];
    u32 pos = row_ptr[r*(NN+1)+d] + atomicAdd(&cnt2[r*NN+d], 1u);
    src_pack[r*NE + pos] = (u32)s;
    const float* es = e_comb + (size_t)(r*NN+s)*16;
    const float* ed = e_comb + (size_t)(r*NN+d)*16 + 8;
    float* ep = e_pack + ((size_t)(r*NE)+pos)*8;
    #pragma unroll
    for (int h = 0; h < 8; h++) ep[h] = leaky(es[h] + ed[h]);
}

// one wave per (node, rel): inline segment softmax + aggregation + relu + residual gate.
__launch_bounds__(256)
__global__ void k_agg(const u32* __restrict__ row_ptr, const u32* __restrict__ src_pack,
                      const float* __restrict__ e_pack, const u16* __restrict__ fsrc,
                      const u16* __restrict__ resb, const float* __restrict__ res_alpha,
                      float* __restrict__ out){
    int r = blockIdx.y;
    int wid = threadIdx.x >> 6;
    int n = blockIdx.x*4 + wid;
    if (n >= NN) return;
    int l = threadIdx.x & 63;
    u32 p0 = row_ptr[r*(NN+1)+n];
    u32 p1 = row_ptr[r*(NN+1)+n+1];
    int deg = (int)(p1 - p0);

    float m = -1e30f, s = 0.f;
    for (int i = (l>>3); i < deg; i += 8){
        float e = e_pack[((size_t)(r*NE) + p0 + i)*8 + (l&7)];
        float mn = fmaxf(m, e);
        s = s*__expf(m - mn) + __expf(e - mn);
        m = mn;
    }
    #pragma unroll
    for (int msk = 8; msk < 64; msk <<= 1){
        float m2 = __shfl_xor(m, msk, 64);
        float s2 = __shfl_xor(s, msk, 64);
        float mn = fmaxf(m, m2);
        s = s*__expf(m - mn) + s2*__expf(m2 - mn);
        m = mn;
    }
    int h = l >> 3;
    float mh = __shfl(m, h, 64);
    float sh = __shfl(s, h, 64);

    float a0=0.f, a1=0.f, a2=0.f, a3=0.f;
    for (int i = 0; i < deg; i++){
        size_t ep = (size_t)(r*NE) + p0 + i;
        float a = __expf(e_pack[ep*8 + h] - mh) / sh;
        u32 src = src_pack[ep];
        ushort4 f = *(const ushort4*)(fsrc + ((size_t)r*NN+src)*256 + l*4);
        a0 += bf2f(f.x)*a; a1 += bf2f(f.y)*a; a2 += bf2f(f.z)*a; a3 += bf2f(f.w)*a;
    }
    int d = nt_dst(r);
    float alpha = 1.f/(1.f + __expf(-res_alpha[d]));
    float beta = 1.f - alpha;
    ushort4 rv = *(const ushort4*)(resb + ((size_t)r*NN+n)*256 + l*4);
    float4 o;
    o.x = fmaxf(a0,0.f)*alpha + bf2f(rv.x)*beta;
    o.y = fmaxf(a1,0.f)*alpha + bf2f(rv.y)*beta;
    o.z = fmaxf(a2,0.f)*alpha + bf2f(rv.z)*beta;
    o.w = fmaxf(a3,0.f)*alpha + bf2f(rv.w)*beta;
    *(float4*)(out + ((size_t)r*NN+n)*256 + l*4) = o;
}

__global__ void k_cross(float* __restrict__ out, const float* __restrict__ cross_attn){
    int n = blockIdx.x; int t = threadIdx.x;   // t = h*32 + d
    size_t i0 = (size_t)n*256 + t;
    size_t i3 = (size_t)3*NN*256 + (size_t)n*256 + t;
    float v0 = out[i0], v3 = out[i3];
    float ca0 = cross_attn[t];
    float ca3 = cross_attn[3*256 + t];
    float p00 = v0*ca0, p30 = v3*ca0, p03 = v0*ca3, p33 = v3*ca3;
    #pragma unroll
    for (int m = 16; m >= 1; m >>= 1){
        p00 += __shfl_xor(p00, m, 64);
        p30 += __shfl_xor(p30, m, 64);
        p03 += __shfl_xor(p03, m, 64);
        p33 += __shfl_xor(p33, m, 64);
    }
    float l0 = leaky(p00), l3 = leaky(p30);
    float mm = fmaxf(l0, l3);
    float w0 = __expf(l0-mm), w3 = __expf(l3-mm);
    float o0 = (w0*v0 + w3*v3) / (w0+w3);
    float q0 = leaky(p03), q3 = leaky(p33);
    float mq = fmaxf(q0, q3);
    float u0 = __expf(q0-mq), u3 = __expf(q3-mq);
    float o3 = (u0*v0 + u3*v3) / (u0+u3);
    out[i0] = o0; out[i3] = o3;
}

__global__ void k_relout(const float* __restrict__ rel_emb, const float* __restrict__ prop_W,
                         const float* __restrict__ prop_b, float* __restrict__ out){
    int r = blockIdx.x; int o = threadIdx.x;
    float acc = prop_b[r*256 + o];
    for (int i = 0; i < 64; i++) acc += rel_emb[r*64+i] * prop_W[(r*64+i)*256 + o];
    out[(size_t)4*NN*256 + r*256 + o] = acc;
}

extern "C" void kernel_launch(void* const* d_in, const int* in_sizes, int n_in,
                              void* d_out, int out_size, void* d_ws, size_t ws_size,
                              hipStream_t stream){
    const float* feat      = (const float*)d_in[0];
    const float* rel_emb   = (const float*)d_in[1];
    const float* node_W    = (const float*)d_in[2];
    const float* rel_W     = (const float*)d_in[3];
    const float* res_W     = (const float*)d_in[4];
    const float* res_b     = (const float*)d_in[5];
    const float* res_alpha = (const float*)d_in[6];
    const float* cross_attn= (const float*)d_in[7];
    const float* prop_W    = (const float*)d_in[8];
    const float* prop_b    = (const float*)d_in[9];
    const int* src_idx     = (const int*)d_in[10];
    const int* dst_idx     = (const int*)d_in[11];
    float* out = (float*)d_out;

    char* ws = (char*)d_ws;
    u32*   cnt     = (u32*)  (ws);                 //    800,000 B (4,NN)
    u32*   cnt2    = (u32*)  (ws + 800000);        //    800,000 B (4,NN)
    u32*   bsum    = (u32*)  (ws + 1600000);       //      4,096 B (4,256)
    u32*   row_ptr = (u32*)  (ws + 1604096);       //    800,016 B (4,NN+1)
    float* ra      = (float*)(ws + 2404112);       //      8,192 B (4,512)
    u16*   WcatT   = (u16*)  (ws + 2412304);       //  1,179,648 B (4,576,256) bf16
    float* e_comb  = (float*)(ws + 3591952);       // 12,800,000 B (4,NN,16) [src|dst]
    u32*   src_pack= (u32*)  (ws + 16391952);      //  3,200,000 B (4,NE)
    float* e_pack  = (float*)(ws + 19591952);      // 25,600,000 B (4,NE,8)
    u16*   fsrc    = (u16*)  (ws + 45191952);      //102,400,000 B (4,NN,256) bf16
    u16*   resb    = (u16*)  (ws + 147591952);     //102,400,000 B (4,NN,256) bf16
    // total: 249,991,952 B

    hipMemsetAsync(cnt, 0, 1604096, stream);  // cnt + cnt2 + bsum

    k_ra<<<4, 256, 0, stream>>>(rel_emb, rel_W, ra);
    k_wcat<<<(4*WCT*256)/256, 256, 0, stream>>>(node_W, res_W, ra, WcatT);
    k_gemm<<<NWG, 256, 0, stream>>>(feat, WcatT, res_b, fsrc, resb, e_comb);

    dim3 geg((NE+255)/256, 4);
    k_count<<<geg, 256, 0, stream>>>(dst_idx, cnt);
    dim3 gsc((NN+255)/256, 4);
    k_scan1<<<gsc, 256, 0, stream>>>(cnt, bsum);
    k_scan2<<<4, 256, 0, stream>>>(bsum);
    k_scan3<<<gsc, 256, 0, stream>>>(cnt, bsum, row_ptr);
    k_scatter<<<geg, 256, 0, stream>>>(src_idx, dst_idx, e_comb, row_ptr, cnt2,
                                       src_pack, e_pack);
    dim3 ga((NN+3)/4, 4);
    k_agg<<<ga, 256, 0, stream>>>(row_ptr, src_pack, e_pack, fsrc, resb, res_alpha, out);

    k_cross<<<NN, 256, 0, stream>>>(out, cross_attn);
    k_relout<<<4, 256, 0, stream>>>(rel_emb, prop_W, prop_b, out);
}